// Round 1
// baseline (503.945 us; speedup 1.0000x reference)
//
#include <hip/hip_runtime.h>
#include <hip/hip_bf16.h>

typedef __bf16 bf16;
typedef __bf16 bf16x4 __attribute__((ext_vector_type(4)));
typedef __bf16 bf16x8 __attribute__((ext_vector_type(8)));
typedef float  f32x4  __attribute__((ext_vector_type(4)));

#define KB 2
#define KS 2048
#define KD 1024
#define KH 16
#define KM (KB*KS)          // 4096 token rows
#define KQKVN 3072
#define KDF 4096

__device__ __forceinline__ f32x4 mfma16(bf16x8 a, bf16x8 b, f32x4 c) {
  return __builtin_amdgcn_mfma_f32_16x16x32_bf16(a, b, c, 0, 0, 0);
}

// ---------------- fp32 -> bf16 elementwise ----------------
__global__ __launch_bounds__(256) void cvt_bf16_kernel(const float* __restrict__ in,
                                                       bf16* __restrict__ out, int n) {
  int i = (blockIdx.x * 256 + threadIdx.x) * 4;
  if (i >= n) return;
  f32x4 v = *reinterpret_cast<const f32x4*>(in + i);
  bf16x4 o;
  o[0] = (bf16)v[0]; o[1] = (bf16)v[1]; o[2] = (bf16)v[2]; o[3] = (bf16)v[3];
  *reinterpret_cast<bf16x4*>(out + i) = o;
}

// ---------------- W[K][N] f32 -> WT[N][K] bf16 (transpose-convert) ----------------
__global__ __launch_bounds__(256) void wtrans_kernel(const float* __restrict__ W,
                                                     bf16* __restrict__ WT,
                                                     int K, int N) {
  __shared__ float tile[32][33];
  const int n0 = blockIdx.x * 32, k0 = blockIdx.y * 32;
  const int tx = threadIdx.x & 31, ty = threadIdx.x >> 5;
#pragma unroll
  for (int j = ty; j < 32; j += 8) tile[j][tx] = W[(size_t)(k0 + j) * N + n0 + tx];
  __syncthreads();
#pragma unroll
  for (int j = ty; j < 32; j += 8) WT[(size_t)(n0 + j) * K + k0 + tx] = (bf16)tile[tx][j];
}

// ---------------- V slice of qkv -> vt[b*H+h][d][s] bf16 ----------------
__global__ __launch_bounds__(256) void vtrans_kernel(const bf16* __restrict__ qkv,
                                                     bf16* __restrict__ vt) {
  __shared__ bf16 tile[64][72];
  const int s0 = blockIdx.x * 64;
  const int bh = blockIdx.y;              // b*16 + h
  const int b = bh >> 4, h = bh & 15;
  const int t = threadIdx.x;
  const int r = t >> 3, c8 = (t & 7) * 8;
#pragma unroll
  for (int rr = r; rr < 64; rr += 32) {
    bf16x8 v = *reinterpret_cast<const bf16x8*>(
        &qkv[(size_t)(b * KS + s0 + rr) * KQKVN + 2048 + h * 64 + c8]);
#pragma unroll
    for (int j = 0; j < 8; j++) tile[rr][c8 + j] = v[j];
  }
  __syncthreads();
#pragma unroll
  for (int dd = r; dd < 64; dd += 32) {
    bf16x8 v;
#pragma unroll
    for (int j = 0; j < 8; j++) v[j] = tile[c8 + j][dd];
    *reinterpret_cast<bf16x8*>(&vt[(size_t)bh * 64 * KS + (size_t)dd * KS + s0 + c8]) = v;
  }
}

// ---------------- GEMM: C[M][N] = A[M][K] @ B, with BT[N][K] given ----------------
// 128x128 tile, BK=32, 4 waves (2x2) of 64x64 each.
template <typename OUT_T, bool RELU, bool HAS_BIAS>
__global__ __launch_bounds__(256) void gemm_bt(const bf16* __restrict__ A,
                                               const bf16* __restrict__ BT,
                                               OUT_T* __restrict__ C,
                                               const float* __restrict__ bias,
                                               int M, int N, int K) {
  constexpr int LDS = 40;   // padded stride (elems): 80B rows -> 2-way conflicts only
  __shared__ bf16 sa[128 * LDS];
  __shared__ bf16 sb[128 * LDS];
  const int t = threadIdx.x;
  const int lane = t & 63;
  const int wid = t >> 6;
  const int wr = wid >> 1, wc = wid & 1;
  const int bm = blockIdx.y * 128;
  const int bn = blockIdx.x * 128;
  const int ar = t >> 2;            // staging row 0..63
  const int ak = (t & 3) * 8;       // staging k-offset
  const int lr = lane & 15;
  const int lk = (lane >> 4) * 8;
  f32x4 acc[4][4] = {};
  for (int k0 = 0; k0 < K; k0 += 32) {
    bf16x8 v0 = *reinterpret_cast<const bf16x8*>(&A[(size_t)(bm + ar) * K + k0 + ak]);
    bf16x8 v1 = *reinterpret_cast<const bf16x8*>(&A[(size_t)(bm + ar + 64) * K + k0 + ak]);
    bf16x8 w0 = *reinterpret_cast<const bf16x8*>(&BT[(size_t)(bn + ar) * K + k0 + ak]);
    bf16x8 w1 = *reinterpret_cast<const bf16x8*>(&BT[(size_t)(bn + ar + 64) * K + k0 + ak]);
    *reinterpret_cast<bf16x8*>(&sa[ar * LDS + ak]) = v0;
    *reinterpret_cast<bf16x8*>(&sa[(ar + 64) * LDS + ak]) = v1;
    *reinterpret_cast<bf16x8*>(&sb[ar * LDS + ak]) = w0;
    *reinterpret_cast<bf16x8*>(&sb[(ar + 64) * LDS + ak]) = w1;
    __syncthreads();
    bf16x8 af[4], bfr[4];
#pragma unroll
    for (int m = 0; m < 4; m++)
      af[m] = *reinterpret_cast<const bf16x8*>(&sa[(wr * 64 + m * 16 + lr) * LDS + lk]);
#pragma unroll
    for (int n = 0; n < 4; n++)
      bfr[n] = *reinterpret_cast<const bf16x8*>(&sb[(wc * 64 + n * 16 + lr) * LDS + lk]);
#pragma unroll
    for (int m = 0; m < 4; m++)
#pragma unroll
      for (int n = 0; n < 4; n++)
        acc[m][n] = mfma16(af[m], bfr[n], acc[m][n]);
    __syncthreads();
  }
  const int rg = (lane >> 4) * 4;
  const int cl = lane & 15;
#pragma unroll
  for (int m = 0; m < 4; m++)
#pragma unroll
    for (int n = 0; n < 4; n++) {
      const int col = bn + wc * 64 + n * 16 + cl;
      float bv = 0.f;
      if (HAS_BIAS) bv = bias[col];
#pragma unroll
      for (int i = 0; i < 4; i++) {
        const int row = bm + wr * 64 + m * 16 + rg + i;
        float v = acc[m][n][i] + bv;
        if (RELU) v = fmaxf(v, 0.f);
        C[(size_t)row * N + col] = (OUT_T)v;
      }
    }
}

// ---------------- flash attention ----------------
// grid: (S/64, B*H); block 256 = 4 waves; each wave owns 16 q-rows.
__global__ __launch_bounds__(256) void attn_kernel(const bf16* __restrict__ qkv,
                                                   const bf16* __restrict__ vt,
                                                   bf16* __restrict__ ctx) {
  const int t = threadIdx.x;
  const int lane = t & 63;
  const int w = t >> 6;
  const int qbase = blockIdx.x * 64 + w * 16;
  const int bh = blockIdx.y;
  const int b = bh >> 4, h = bh & 15;
  const int lr = lane & 15;
  const int lk = (lane >> 4) * 8;
  const int rg = (lane >> 4) * 4;
  const int cl = lane & 15;

  __shared__ bf16 lds_p[4][16 * 48];    // per-wave P tile, stride 48 elems (96B)
  bf16* pw = &lds_p[w][0];

  const size_t rowQ = (size_t)(b * KS + qbase + lr) * KQKVN + h * 64;
  bf16x8 aq0 = *reinterpret_cast<const bf16x8*>(&qkv[rowQ + lk]);
  bf16x8 aq1 = *reinterpret_cast<const bf16x8*>(&qkv[rowQ + 32 + lk]);

  f32x4 accd[4] = {};
  float mrow[4], lrow[4];
#pragma unroll
  for (int i = 0; i < 4; i++) { mrow[i] = -1e30f; lrow[i] = 0.f; }

  const size_t kbase = (size_t)(b * KS) * KQKVN + 1024 + h * 64;
  const size_t vbase = (size_t)bh * 64 * KS;

  for (int kt = 0; kt < KS; kt += 32) {
    f32x4 sc[2];
#pragma unroll
    for (int ct = 0; ct < 2; ct++) {
      const size_t rk = kbase + (size_t)(kt + ct * 16 + lr) * KQKVN;
      bf16x8 bk0 = *reinterpret_cast<const bf16x8*>(&qkv[rk + lk]);
      bf16x8 bk1 = *reinterpret_cast<const bf16x8*>(&qkv[rk + 32 + lk]);
      f32x4 s = {};
      s = mfma16(aq0, bk0, s);
      s = mfma16(aq1, bk1, s);
      sc[ct] = s * 0.125f;              // 1/sqrt(64)
    }
    // online softmax (row r = rg+i lives in the 16 lanes of this lane-group)
    float tmax[4], tsum[4];
#pragma unroll
    for (int i = 0; i < 4; i++) tmax[i] = fmaxf(sc[0][i], sc[1][i]);
#pragma unroll
    for (int off = 1; off < 16; off <<= 1)
#pragma unroll
      for (int i = 0; i < 4; i++) tmax[i] = fmaxf(tmax[i], __shfl_xor(tmax[i], off, 64));
    float mnew[4], alpha[4];
#pragma unroll
    for (int i = 0; i < 4; i++) {
      mnew[i] = fmaxf(mrow[i], tmax[i]);
      alpha[i] = __expf(mrow[i] - mnew[i]);
      mrow[i] = mnew[i];
    }
#pragma unroll
    for (int i = 0; i < 4; i++) {
      sc[0][i] = __expf(sc[0][i] - mnew[i]);
      sc[1][i] = __expf(sc[1][i] - mnew[i]);
      tsum[i] = sc[0][i] + sc[1][i];
    }
#pragma unroll
    for (int off = 1; off < 16; off <<= 1)
#pragma unroll
      for (int i = 0; i < 4; i++) tsum[i] += __shfl_xor(tsum[i], off, 64);
#pragma unroll
    for (int i = 0; i < 4; i++) lrow[i] = lrow[i] * alpha[i] + tsum[i];
#pragma unroll
    for (int dt = 0; dt < 4; dt++)
#pragma unroll
      for (int i = 0; i < 4; i++) accd[dt][i] *= alpha[i];
    // P (C-layout) -> LDS bf16 -> A-layout fragment
#pragma unroll
    for (int ct = 0; ct < 2; ct++)
#pragma unroll
      for (int i = 0; i < 4; i++)
        pw[(rg + i) * 48 + ct * 16 + cl] = (bf16)sc[ct][i];
    bf16x8 ap = *reinterpret_cast<const bf16x8*>(&pw[lr * 48 + lk]);
    // PV
#pragma unroll
    for (int dt = 0; dt < 4; dt++) {
      bf16x8 bv = *reinterpret_cast<const bf16x8*>(
          &vt[vbase + (size_t)(dt * 16 + lr) * KS + kt + lk]);
      accd[dt] = mfma16(ap, bv, accd[dt]);
    }
  }
  // epilogue
#pragma unroll
  for (int dt = 0; dt < 4; dt++)
#pragma unroll
    for (int i = 0; i < 4; i++) {
      float v = accd[dt][i] / lrow[i];
      ctx[(size_t)(b * KS + qbase + rg + i) * KD + h * 64 + dt * 16 + cl] = (bf16)v;
    }
}

// ---------------- residual add + LayerNorm ----------------
// row = blockIdx.x; A (f32 or bf16) + Bsum (f32) -> out (bf16 or f32)
template <bool ABF, bool OBF>
__global__ __launch_bounds__(256) void ln_kernel(const void* __restrict__ aptr,
                                                 const float* __restrict__ bsum,
                                                 const float* __restrict__ g,
                                                 const float* __restrict__ bet,
                                                 void* __restrict__ outp) {
  const int row = blockIdx.x;
  const int t = threadIdx.x;
  const int lane = t & 63, wid = t >> 6;
  float v[4];
  {
    f32x4 bv = *reinterpret_cast<const f32x4*>(&bsum[(size_t)row * KD + t * 4]);
    if (ABF) {
      bf16x4 av = *reinterpret_cast<const bf16x4*>(
          (const bf16*)aptr + (size_t)row * KD + t * 4);
#pragma unroll
      for (int j = 0; j < 4; j++) v[j] = (float)av[j] + bv[j];
    } else {
      f32x4 av = *reinterpret_cast<const f32x4*>(
          (const float*)aptr + (size_t)row * KD + t * 4);
#pragma unroll
      for (int j = 0; j < 4; j++) v[j] = av[j] + bv[j];
    }
  }
  float s = 0.f, s2 = 0.f;
#pragma unroll
  for (int j = 0; j < 4; j++) { s += v[j]; s2 += v[j] * v[j]; }
#pragma unroll
  for (int off = 32; off; off >>= 1) {
    s += __shfl_xor(s, off, 64);
    s2 += __shfl_xor(s2, off, 64);
  }
  __shared__ float red[8];
  if (lane == 0) { red[wid] = s; red[wid + 4] = s2; }
  __syncthreads();
  s = red[0] + red[1] + red[2] + red[3];
  s2 = red[4] + red[5] + red[6] + red[7];
  const float mu = s * (1.f / KD);
  const float var = s2 * (1.f / KD) - mu * mu;
  const float rs = rsqrtf(var + 1e-5f);
  if (OBF) {
    bf16x4 o;
#pragma unroll
    for (int j = 0; j < 4; j++)
      o[j] = (bf16)((v[j] - mu) * rs * g[t * 4 + j] + bet[t * 4 + j]);
    *reinterpret_cast<bf16x4*>((bf16*)outp + (size_t)row * KD + t * 4) = o;
  } else {
    f32x4 o;
#pragma unroll
    for (int j = 0; j < 4; j++)
      o[j] = (v[j] - mu) * rs * g[t * 4 + j] + bet[t * 4 + j];
    *reinterpret_cast<f32x4*>((float*)outp + (size_t)row * KD + t * 4) = o;
  }
}

extern "C" void kernel_launch(void* const* d_in, const int* in_sizes, int n_in,
                              void* d_out, int out_size, void* d_ws, size_t ws_size,
                              hipStream_t stream) {
  const float* x     = (const float*)d_in[0];
  const float* wq    = (const float*)d_in[1];
  const float* wk    = (const float*)d_in[2];
  const float* wv    = (const float*)d_in[3];
  const float* wo    = (const float*)d_in[4];
  const float* w1    = (const float*)d_in[5];
  const float* b1    = (const float*)d_in[6];
  const float* w2    = (const float*)d_in[7];
  const float* b2    = (const float*)d_in[8];
  const float* ln1g  = (const float*)d_in[9];
  const float* ln1b  = (const float*)d_in[10];
  const float* ln2g  = (const float*)d_in[11];
  const float* ln2b  = (const float*)d_in[12];
  float* out = (float*)d_out;

  char* ws = (char*)d_ws;
  bf16*  x_bf   = (bf16*)(ws + 0);            // 8.39 MB; later reused as ctx
  bf16*  wqkvT  = (bf16*)(ws + 8388608);      // 6.29 MB
  bf16*  woT    = (bf16*)(ws + 14680064);     // 2.10 MB
  bf16*  w1T    = (bf16*)(ws + 16777216);     // 8.39 MB
  bf16*  w2T    = (bf16*)(ws + 25165824);     // 8.39 MB
  bf16*  qkv    = (bf16*)(ws + 33554432);     // 25.17 MB; ffn1 reuses qkv+vt span
  bf16*  vt     = (bf16*)(ws + 58720256);     // 8.39 MB
  float* proj   = (float*)(ws + 67108864);    // 16.78 MB; ffn2 reuses
  bf16*  h_bf   = (bf16*)(ws + 83886080);     // 8.39 MB   (end: 92.27 MB)
  bf16*  ctx    = x_bf;
  bf16*  ffn1   = qkv;
  float* ffn2   = proj;

  // 1) conversions / transposes
  cvt_bf16_kernel<<<dim3(KM * KD / 1024), 256, 0, stream>>>(x, x_bf, KM * KD);
  wtrans_kernel<<<dim3(32, 32), 256, 0, stream>>>(wq, wqkvT, KD, KD);
  wtrans_kernel<<<dim3(32, 32), 256, 0, stream>>>(wk, wqkvT + 1024 * 1024, KD, KD);
  wtrans_kernel<<<dim3(32, 32), 256, 0, stream>>>(wv, wqkvT + 2048 * 1024, KD, KD);
  wtrans_kernel<<<dim3(32, 32), 256, 0, stream>>>(wo, woT, KD, KD);
  wtrans_kernel<<<dim3(128, 32), 256, 0, stream>>>(w1, w1T, KD, KDF);
  wtrans_kernel<<<dim3(32, 128), 256, 0, stream>>>(w2, w2T, KDF, KD);

  // 2) QKV projection: [4096,1024] @ -> [4096,3072] bf16
  gemm_bt<bf16, false, false><<<dim3(KQKVN / 128, KM / 128), 256, 0, stream>>>(
      x_bf, wqkvT, qkv, nullptr, KM, KQKVN, KD);

  // 3) V transpose per head
  vtrans_kernel<<<dim3(KS / 64, KB * KH), 256, 0, stream>>>(qkv, vt);

  // 4) flash attention -> ctx bf16 [4096,1024]
  attn_kernel<<<dim3(KS / 64, KB * KH), 256, 0, stream>>>(qkv, vt, ctx);

  // 5) output projection -> proj f32
  gemm_bt<float, false, false><<<dim3(KD / 128, KM / 128), 256, 0, stream>>>(
      ctx, woT, proj, nullptr, KM, KD, KD);

  // 6) LN1: h = LN(x + proj) -> h_bf (bf16)
  ln_kernel<false, true><<<dim3(KM), 256, 0, stream>>>(x, proj, ln1g, ln1b, h_bf);

  // 7) FFN1: relu(h @ w1 + b1) -> ffn1 bf16 [4096,4096]
  gemm_bt<bf16, true, true><<<dim3(KDF / 128, KM / 128), 256, 0, stream>>>(
      h_bf, w1T, ffn1, b1, KM, KDF, KD);

  // 8) FFN2: ffn1 @ w2 + b2 -> ffn2 f32 [4096,1024]
  gemm_bt<float, false, true><<<dim3(KD / 128, KM / 128), 256, 0, stream>>>(
      ffn1, w2T, ffn2, b2, KM, KD, KDF);

  // 9) LN2: out = LN(h + ffn2) -> d_out f32
  ln_kernel<true, false><<<dim3(KM), 256, 0, stream>>>(h_bf, ffn2, ln2g, ln2b, out);
}